// Round 5
// baseline (135.889 us; speedup 1.0000x reference)
//
#include <hip/hip_runtime.h>

typedef __bf16 bf16x8 __attribute__((ext_vector_type(8)));
typedef float f32x4 __attribute__((ext_vector_type(4)));
typedef unsigned short u16;

#define LSEQ 2048
#define DMODEL 1024
#define HEADD 64
#define NBATCH 8

__device__ __forceinline__ u16 cvt(float f) {
  __bf16 h = (__bf16)f;               // native v_cvt (RNE)
  return __builtin_bit_cast(u16, h);
}

// ---------------------------------------------------------------------------
// Kernel 0: W [1024][64] fp32  ->  Wt [64][1024] bf16   (x3 weights)
// ---------------------------------------------------------------------------
__global__ void wt_kernel(const float* __restrict__ Wk, const float* __restrict__ Wq,
                          const float* __restrict__ Wv, u16* __restrict__ wt) {
  int n = blockIdx.x;   // head-dim column of W = row of Wt
  int p = blockIdx.y;   // which weight
  const float* W = (p == 0) ? Wk : ((p == 1) ? Wq : Wv);
  u16* dst = wt + ((size_t)p * HEADD + n) * DMODEL;
  for (int k = threadIdx.x; k < DMODEL; k += blockDim.x)
    dst[k] = cvt(W[(size_t)k * HEADD + n]);
}

// ---------------------------------------------------------------------------
// Kernel 1: projections, strip-streaming form (DRAM row-buffer friendly).
// Block = 1 wave owns a 16-row strip = 64KB CONTIGUOUS global memory.
// Stage: stream the strip sequentially (8 groups x 8KB, 2-group rolling
// pipeline, <=16 loads in flight), cvt->bf16, ds_write into XOR-swizzled
// [16][1024] bf16 tile. Compute: 32 k-steps, A-frag ds_read_b128 + W frags
// from L2, 1-deep register pipeline. 5 blocks/CU (32KB LDS each).
// p==0 -> K bf16 ; p==1 -> Q*0.125 ; p==2 -> V^T [b][64][2048]
// ---------------------------------------------------------------------------
__global__ __launch_bounds__(64) void proj_kernel(
    const float* __restrict__ ik, const float* __restrict__ iq, const float* __restrict__ iv,
    const u16* __restrict__ wt, u16* __restrict__ Kb, u16* __restrict__ Qb,
    u16* __restrict__ Vt) {
  __shared__ __align__(16) u16 As[16 * 1024];  // 32 KB swizzled bf16 strip
  int p = blockIdx.y;
  const float* A = (p == 0) ? ik : ((p == 1) ? iq : iv);
  const u16* W = wt + (size_t)p * HEADD * DMODEL;
  int t = threadIdx.x;            // 0..63 (one wave)
  int l15 = t & 15, g = t >> 4;
  int rowbase = blockIdx.x * 16;  // strip start row (of 16384)
  const float4* src = (const float4*)(A + (size_t)rowbase * DMODEL);

  // ---- stage: stream 64KB contiguous; group jg covers 8KB ----
  // float4 index f = jg*512 + i*64 + t ; row r = f>>8 ; col = (f*4)&1023
  float4 stg[2][8];
  auto issue = [&](int jg, int buf) {
#pragma unroll
    for (int i = 0; i < 8; ++i)
      stg[buf][i] = src[jg * 512 + i * 64 + t];
  };
  auto commit = [&](int jg, int buf) {
    char* base = (char*)As;
#pragma unroll
    for (int i = 0; i < 8; ++i) {
      int r = jg * 2 + (i >> 2);
      int byte = (((i & 3) * 512 + t * 8) ^ ((r & 7) << 4)) + r * 2048;
      ushort4 pk;
      pk.x = cvt(stg[buf][i].x); pk.y = cvt(stg[buf][i].y);
      pk.z = cvt(stg[buf][i].z); pk.w = cvt(stg[buf][i].w);
      *(ushort4*)(base + byte) = pk;
    }
  };

  issue(0, 0);
#pragma unroll
  for (int jg = 0; jg < 8; ++jg) {
    if (jg < 7) issue(jg + 1, (jg + 1) & 1);
    commit(jg, jg & 1);
  }
  __syncthreads();

  // ---- compute: 32 k-steps, 1-deep pipeline ----
  int swz = (l15 & 7) << 4;
  const char* abase = (const char*)As + l15 * 2048;
  auto lda = [&](int ks) {
    return *(const bf16x8*)(abase + ((ks * 64 + 16 * g) ^ swz));
  };

  f32x4 acc[4] = {};  // [c]: row = rowbase+4g+r, col = 16c+l15
  bf16x8 af = lda(0);
  bf16x8 wf[4];
#pragma unroll
  for (int c = 0; c < 4; ++c)
    wf[c] = *(const bf16x8*)(W + (size_t)(16 * c + l15) * DMODEL + 8 * g);

  for (int ks = 0; ks < 32; ++ks) {
    bf16x8 afn;
    bf16x8 wfn[4];
    if (ks < 31) {
      afn = lda(ks + 1);
#pragma unroll
      for (int c = 0; c < 4; ++c)
        wfn[c] = *(const bf16x8*)(W + (size_t)(16 * c + l15) * DMODEL + (ks + 1) * 32 + 8 * g);
    }
#pragma unroll
    for (int c = 0; c < 4; ++c)
      acc[c] = __builtin_amdgcn_mfma_f32_16x16x32_bf16(af, wf[c], acc[c], 0, 0, 0);
    af = afn;
#pragma unroll
    for (int c = 0; c < 4; ++c) wf[c] = wfn[c];
  }

  // ---- epilogue ----
  if (p == 2) {
    // store V transposed: Vt[b][d][tok], pack 4 consecutive tokens -> 8B store
    int row0 = rowbase + 4 * g;
    int b = row0 >> 11, tok = row0 & 2047;
#pragma unroll
    for (int c = 0; c < 4; ++c) {
      int d = 16 * c + l15;
      ushort4 pk;
      pk.x = cvt(acc[c][0]); pk.y = cvt(acc[c][1]);
      pk.z = cvt(acc[c][2]); pk.w = cvt(acc[c][3]);
      *(ushort4*)(Vt + ((size_t)b * HEADD + d) * LSEQ + tok) = pk;
    }
  } else {
    u16* dst = (p == 0) ? Kb : Qb;
    float s = (p == 1) ? 0.125f : 1.0f;  // fold softmax scale into Q (exact pow2)
#pragma unroll
    for (int c = 0; c < 4; ++c)
#pragma unroll
      for (int r = 0; r < 4; ++r)
        dst[(size_t)(rowbase + 4 * g + r) * HEADD + 16 * c + l15] = cvt(acc[c][r] * s);
  }
}

// ---------------------------------------------------------------------------
// Kernel 2: causal flash attention. 2 waves/block, wave owns 16 q-rows.
// Swapped QK^T: S^T = mfma(K, Q^T) so lane's scores all belong to q = lane&15.
// P transposed to PV A-frag layout via small padded per-wave LDS buffer.
// V^T gives contiguous 16B PV B-frag loads.
// ---------------------------------------------------------------------------
__global__ __launch_bounds__(128) void attn_kernel(
    const u16* __restrict__ Kb, const u16* __restrict__ Qb, const u16* __restrict__ Vt,
    float* __restrict__ out) {
  __shared__ __align__(16) u16 plds[2][16 * 40];  // per-wave P tile [16q][32k], pad->40
  int lane = threadIdx.x & 63;
  int wv = threadIdx.x >> 6;
  int l15 = lane & 15, g = lane >> 4;
  int b = blockIdx.y;
  int qt = 63 - (int)blockIdx.x;          // heavy tiles first
  int qbase = qt * 32 + wv * 16;          // within batch

  const u16* Qp = Qb + ((size_t)b * LSEQ + qbase) * HEADD;
  const u16* Kp = Kb + (size_t)b * LSEQ * HEADD;
  const u16* Vp = Vt + (size_t)b * HEADD * LSEQ;

  bf16x8 qf[2];
#pragma unroll
  for (int ds = 0; ds < 2; ++ds)
    qf[ds] = *(const bf16x8*)(Qp + (size_t)l15 * HEADD + 32 * ds + 8 * g);

  f32x4 acc[4] = {};        // [c]: reg r -> q-row qbase+4g+r, col d=16c+l15
  float m = -1e30f, lsum = 0.f;
  int q_abs = qbase + l15;
  int ntiles = (qbase + 47) >> 5;

  for (int t = 0; t < ntiles; ++t) {
    int kbase = t * 32;
    f32x4 sacc[2] = {};     // [f]: key = kbase+16f+4g+r, q = qbase+l15
#pragma unroll
    for (int f = 0; f < 2; ++f)
#pragma unroll
      for (int ds = 0; ds < 2; ++ds) {
        bf16x8 kf = *(const bf16x8*)(Kp + (size_t)(kbase + 16 * f + l15) * HEADD + 32 * ds + 8 * g);
        sacc[f] = __builtin_amdgcn_mfma_f32_16x16x32_bf16(kf, qf[ds], sacc[f], 0, 0, 0);
      }

    // causal mask + row-max (row == this lane's q)
    float sv[2][4];
    float tmax = -1e30f;
#pragma unroll
    for (int f = 0; f < 2; ++f)
#pragma unroll
      for (int r = 0; r < 4; ++r) {
        int key = kbase + 16 * f + 4 * g + r;
        float s = (key <= q_abs) ? sacc[f][r] : -1e30f;
        sv[f][r] = s;
        tmax = fmaxf(tmax, s);
      }
    tmax = fmaxf(tmax, __shfl_xor(tmax, 16));
    tmax = fmaxf(tmax, __shfl_xor(tmax, 32));
    float mnew = fmaxf(m, tmax);
    float al = __expf(m - mnew);
    float pv[2][4];
    float rs = 0.f;
#pragma unroll
    for (int f = 0; f < 2; ++f)
#pragma unroll
      for (int r = 0; r < 4; ++r) {
        pv[f][r] = __expf(sv[f][r] - mnew);
        rs += pv[f][r];
      }
    rs += __shfl_xor(rs, 16);
    rs += __shfl_xor(rs, 32);
    lsum = lsum * al + rs;
    m = mnew;

    // rescale O accumulator: row 4g+r's factor lives at lane (4g+r) (group 0 copy)
    float alr[4];
#pragma unroll
    for (int r = 0; r < 4; ++r) alr[r] = __shfl(al, 4 * g + r);
#pragma unroll
    for (int c = 0; c < 4; ++c)
#pragma unroll
      for (int r = 0; r < 4; ++r) acc[c][r] *= alr[r];

    // P -> LDS in PV A-frag layout: P[q=l15][key 16f+4g + r]
#pragma unroll
    for (int f = 0; f < 2; ++f) {
      ushort4 pk;
      pk.x = cvt(pv[f][0]); pk.y = cvt(pv[f][1]);
      pk.z = cvt(pv[f][2]); pk.w = cvt(pv[f][3]);
      *(ushort4*)&plds[wv][l15 * 40 + 16 * f + 4 * g] = pk;
    }
    bf16x8 ap = *(const bf16x8*)&plds[wv][l15 * 40 + 8 * g];

    // PV: B-frag = V[kbase+8g+j][16c+l15] = Vt[16c+l15][kbase+8g+j] (contiguous)
#pragma unroll
    for (int c = 0; c < 4; ++c) {
      bf16x8 vf = *(const bf16x8*)(Vp + (size_t)(16 * c + l15) * LSEQ + kbase + 8 * g);
      acc[c] = __builtin_amdgcn_mfma_f32_16x16x32_bf16(ap, vf, acc[c], 0, 0, 0);
    }
  }

  // normalize and store fp32 output
  float li[4];
#pragma unroll
  for (int r = 0; r < 4; ++r) {
    float lv = __shfl(lsum, 4 * g + r);
    li[r] = 1.0f / lv;
  }
#pragma unroll
  for (int c = 0; c < 4; ++c)
#pragma unroll
    for (int r = 0; r < 4; ++r)
      out[((size_t)b * LSEQ + qbase + 4 * g + r) * HEADD + 16 * c + l15] = acc[c][r] * li[r];
}

// ---------------------------------------------------------------------------
extern "C" void kernel_launch(void* const* d_in, const int* in_sizes, int n_in,
                              void* d_out, int out_size, void* d_ws, size_t ws_size,
                              hipStream_t stream) {
  const float* idx_k = (const float*)d_in[0];
  const float* idx_q = (const float*)d_in[1];
  const float* idx_v = (const float*)d_in[2];
  // d_in[3] = msk : causal mask is applied analytically, never read
  const float* Wk = (const float*)d_in[4];
  const float* Wq = (const float*)d_in[5];
  const float* Wv = (const float*)d_in[6];
  float* out = (float*)d_out;

  char* ws = (char*)d_ws;
  const size_t WT_BYTES = (size_t)3 * HEADD * DMODEL * 2;        // 384 KB
  const size_t MAT_BYTES = (size_t)NBATCH * LSEQ * HEADD * 2;    // 2 MB each
  u16* wt = (u16*)ws;
  u16* Kb = (u16*)(ws + WT_BYTES);
  u16* Qb = (u16*)(ws + WT_BYTES + MAT_BYTES);
  u16* Vt = (u16*)(ws + WT_BYTES + 2 * MAT_BYTES);

  hipLaunchKernelGGL(wt_kernel, dim3(64, 3), dim3(256), 0, stream, Wk, Wq, Wv, wt);
  hipLaunchKernelGGL(proj_kernel, dim3(1024, 3), dim3(64), 0, stream,
                     idx_k, idx_q, idx_v, wt, Kb, Qb, Vt);
  hipLaunchKernelGGL(attn_kernel, dim3(64, NBATCH), dim3(128), 0, stream, Kb, Qb, Vt, out);
}

// Round 6
// 97.679 us; speedup vs baseline: 1.3912x; 1.3912x over previous
//
#include <hip/hip_runtime.h>

typedef __bf16 bf16x8 __attribute__((ext_vector_type(8)));
typedef float f32x4 __attribute__((ext_vector_type(4)));
typedef unsigned short u16;

#define LSEQ 2048
#define DMODEL 1024
#define HEADD 64
#define NBATCH 8

__device__ __forceinline__ u16 cvt(float f) {
  __bf16 h = (__bf16)f;               // native v_cvt (RNE)
  return __builtin_bit_cast(u16, h);
}

__device__ __forceinline__ bf16x8 pack8(float4 a, float4 b) {
  bf16x8 r;
  r[0] = (__bf16)a.x; r[1] = (__bf16)a.y; r[2] = (__bf16)a.z; r[3] = (__bf16)a.w;
  r[4] = (__bf16)b.x; r[5] = (__bf16)b.y; r[6] = (__bf16)b.z; r[7] = (__bf16)b.w;
  return r;
}

// ---------------------------------------------------------------------------
// Kernel 0: pack W [1024][64] fp32 into MFMA B-FRAGMENT order (bf16):
//   wp[((p*4 + c)*32 + ks)*512 + lane*8 + j] = W_p[k = ks*32 + 8*(lane>>4) + j]
//                                                  [col = 16*c + (lane&15)]
// so a wave's B-frag load in proj is ONE contiguous 1KB read (16 lines,
// vs 32 scattered lines from row-major Wt — that scatter was the R1-R5
// bottleneck: ~49K line-touches/CU from W alone).
// ---------------------------------------------------------------------------
__global__ __launch_bounds__(256) void wt_kernel(
    const float* __restrict__ Wk, const float* __restrict__ Wq,
    const float* __restrict__ Wv, u16* __restrict__ wp) {
  int idx = blockIdx.x * 256 + threadIdx.x;   // 0 .. 3*4*32*512-1 (196608)
  int j = idx & 7;
  int lane = (idx >> 3) & 63;
  int ks = (idx >> 9) & 31;
  int c = (idx >> 14) & 3;
  int p = idx >> 16;
  const float* W = (p == 0) ? Wk : ((p == 1) ? Wq : Wv);
  int k = ks * 32 + 8 * (lane >> 4) + j;
  int col = 16 * c + (lane & 15);
  wp[idx] = cvt(W[(size_t)k * HEADD + col]);
}

// ---------------------------------------------------------------------------
// Kernel 1: projections, direct-register form with packed-W fragments.
// Block = 128 thr (2 waves); wave owns 32 rows x 64 cols. Grid (256,3) =
// 768 blocks -> even 3 blocks/CU, 6 waves/CU. Per k-step per wave:
// 4 coalesced float4 A-loads (HBM, lines touched once) + 4 contiguous 1KB
// W-frag loads (L2-resident) + 8 MFMA. 1-deep prefetch on both streams.
// p==0 -> K bf16 ; p==1 -> Q*0.125 ; p==2 -> V^T [b][64][2048]
// ---------------------------------------------------------------------------
__global__ __launch_bounds__(128) void proj_kernel(
    const float* __restrict__ ik, const float* __restrict__ iq, const float* __restrict__ iv,
    const u16* __restrict__ wp, u16* __restrict__ Kb, u16* __restrict__ Qb,
    u16* __restrict__ Vt) {
  int p = blockIdx.y;
  const float* A = (p == 0) ? ik : ((p == 1) ? iq : iv);
  const u16* Wp = wp + (size_t)p * 4 * 32 * 512;   // [c][ks][512]
  int t = threadIdx.x;
  int lane = t & 63;
  int wv = t >> 6;
  int l15 = lane & 15, g = lane >> 4;
  int rowbase = blockIdx.x * 64 + wv * 32;
  const float* a0 = A + (size_t)(rowbase + l15) * DMODEL + 8 * g;
  const float* a1 = A + (size_t)(rowbase + 16 + l15) * DMODEL + 8 * g;

  f32x4 acc[2][4] = {};  // [mf][c]: row = rowbase+16mf+4g+r, col = 16c+l15

  float4 f00 = *(const float4*)(a0);
  float4 f01 = *(const float4*)(a0 + 4);
  float4 f10 = *(const float4*)(a1);
  float4 f11 = *(const float4*)(a1 + 4);
  bf16x8 wf[4];
#pragma unroll
  for (int c = 0; c < 4; ++c)
    wf[c] = *(const bf16x8*)(Wp + (c * 32 + 0) * 512 + lane * 8);

  for (int ks = 0; ks < 32; ++ks) {
    float4 n00, n01, n10, n11;
    bf16x8 wn[4];
    if (ks < 31) {
      n00 = *(const float4*)(a0 + (ks + 1) * 32);
      n01 = *(const float4*)(a0 + (ks + 1) * 32 + 4);
      n10 = *(const float4*)(a1 + (ks + 1) * 32);
      n11 = *(const float4*)(a1 + (ks + 1) * 32 + 4);
#pragma unroll
      for (int c = 0; c < 4; ++c)
        wn[c] = *(const bf16x8*)(Wp + (c * 32 + ks + 1) * 512 + lane * 8);
    }
    bf16x8 af0 = pack8(f00, f01);
    bf16x8 af1 = pack8(f10, f11);
#pragma unroll
    for (int c = 0; c < 4; ++c) {
      acc[0][c] = __builtin_amdgcn_mfma_f32_16x16x32_bf16(af0, wf[c], acc[0][c], 0, 0, 0);
      acc[1][c] = __builtin_amdgcn_mfma_f32_16x16x32_bf16(af1, wf[c], acc[1][c], 0, 0, 0);
    }
    f00 = n00; f01 = n01; f10 = n10; f11 = n11;
#pragma unroll
    for (int c = 0; c < 4; ++c) wf[c] = wn[c];
  }

  if (p == 2) {
    // store V transposed: Vt[b][d][tok], pack 4 consecutive tokens -> 8B store
#pragma unroll
    for (int mf = 0; mf < 2; ++mf) {
      int row0 = rowbase + mf * 16 + 4 * g;
      int b = row0 >> 11, tok = row0 & 2047;
#pragma unroll
      for (int c = 0; c < 4; ++c) {
        int d = 16 * c + l15;
        ushort4 pk;
        pk.x = cvt(acc[mf][c][0]); pk.y = cvt(acc[mf][c][1]);
        pk.z = cvt(acc[mf][c][2]); pk.w = cvt(acc[mf][c][3]);
        *(ushort4*)(Vt + ((size_t)b * HEADD + d) * LSEQ + tok) = pk;
      }
    }
  } else {
    u16* dst = (p == 0) ? Kb : Qb;
    float s = (p == 1) ? 0.125f : 1.0f;  // fold softmax scale into Q (exact pow2)
#pragma unroll
    for (int mf = 0; mf < 2; ++mf)
#pragma unroll
      for (int c = 0; c < 4; ++c)
#pragma unroll
        for (int r = 0; r < 4; ++r)
          dst[(size_t)(rowbase + mf * 16 + 4 * g + r) * HEADD + 16 * c + l15] =
              cvt(acc[mf][c][r] * s);
  }
}

// ---------------------------------------------------------------------------
// Kernel 2: causal flash attention. 2 waves/block, wave owns 16 q-rows.
// Swapped QK^T: S^T = mfma(K, Q^T) so lane's scores all belong to q = lane&15.
// P transposed to PV A-frag layout via small padded per-wave LDS buffer.
// V^T gives contiguous 16B PV B-frag loads.
// ---------------------------------------------------------------------------
__global__ __launch_bounds__(128) void attn_kernel(
    const u16* __restrict__ Kb, const u16* __restrict__ Qb, const u16* __restrict__ Vt,
    float* __restrict__ out) {
  __shared__ __align__(16) u16 plds[2][16 * 40];  // per-wave P tile [16q][32k], pad->40
  int lane = threadIdx.x & 63;
  int wv = threadIdx.x >> 6;
  int l15 = lane & 15, g = lane >> 4;
  int b = blockIdx.y;
  int qt = 63 - (int)blockIdx.x;          // heavy tiles first
  int qbase = qt * 32 + wv * 16;          // within batch

  const u16* Qp = Qb + ((size_t)b * LSEQ + qbase) * HEADD;
  const u16* Kp = Kb + (size_t)b * LSEQ * HEADD;
  const u16* Vp = Vt + (size_t)b * HEADD * LSEQ;

  bf16x8 qf[2];
#pragma unroll
  for (int ds = 0; ds < 2; ++ds)
    qf[ds] = *(const bf16x8*)(Qp + (size_t)l15 * HEADD + 32 * ds + 8 * g);

  f32x4 acc[4] = {};        // [c]: reg r -> q-row qbase+4g+r, col d=16c+l15
  float m = -1e30f, lsum = 0.f;
  int q_abs = qbase + l15;
  int ntiles = (qbase + 47) >> 5;

  for (int t = 0; t < ntiles; ++t) {
    int kbase = t * 32;
    f32x4 sacc[2] = {};     // [f]: key = kbase+16f+4g+r, q = qbase+l15
#pragma unroll
    for (int f = 0; f < 2; ++f)
#pragma unroll
      for (int ds = 0; ds < 2; ++ds) {
        bf16x8 kf = *(const bf16x8*)(Kp + (size_t)(kbase + 16 * f + l15) * HEADD + 32 * ds + 8 * g);
        sacc[f] = __builtin_amdgcn_mfma_f32_16x16x32_bf16(kf, qf[ds], sacc[f], 0, 0, 0);
      }

    // causal mask + row-max (row == this lane's q)
    float sv[2][4];
    float tmax = -1e30f;
#pragma unroll
    for (int f = 0; f < 2; ++f)
#pragma unroll
      for (int r = 0; r < 4; ++r) {
        int key = kbase + 16 * f + 4 * g + r;
        float s = (key <= q_abs) ? sacc[f][r] : -1e30f;
        sv[f][r] = s;
        tmax = fmaxf(tmax, s);
      }
    tmax = fmaxf(tmax, __shfl_xor(tmax, 16));
    tmax = fmaxf(tmax, __shfl_xor(tmax, 32));
    float mnew = fmaxf(m, tmax);
    float al = __expf(m - mnew);
    float pv[2][4];
    float rs = 0.f;
#pragma unroll
    for (int f = 0; f < 2; ++f)
#pragma unroll
      for (int r = 0; r < 4; ++r) {
        pv[f][r] = __expf(sv[f][r] - mnew);
        rs += pv[f][r];
      }
    rs += __shfl_xor(rs, 16);
    rs += __shfl_xor(rs, 32);
    lsum = lsum * al + rs;
    m = mnew;

    // rescale O accumulator: row 4g+r's factor lives at lane (4g+r) (group 0 copy)
    float alr[4];
#pragma unroll
    for (int r = 0; r < 4; ++r) alr[r] = __shfl(al, 4 * g + r);
#pragma unroll
    for (int c = 0; c < 4; ++c)
#pragma unroll
      for (int r = 0; r < 4; ++r) acc[c][r] *= alr[r];

    // P -> LDS in PV A-frag layout: P[q=l15][key 16f+4g + r]
#pragma unroll
    for (int f = 0; f < 2; ++f) {
      ushort4 pk;
      pk.x = cvt(pv[f][0]); pk.y = cvt(pv[f][1]);
      pk.z = cvt(pv[f][2]); pk.w = cvt(pv[f][3]);
      *(ushort4*)&plds[wv][l15 * 40 + 16 * f + 4 * g] = pk;
    }
    bf16x8 ap = *(const bf16x8*)&plds[wv][l15 * 40 + 8 * g];

    // PV: B-frag = V[kbase+8g+j][16c+l15] = Vt[16c+l15][kbase+8g+j] (contiguous)
#pragma unroll
    for (int c = 0; c < 4; ++c) {
      bf16x8 vf = *(const bf16x8*)(Vp + (size_t)(16 * c + l15) * LSEQ + kbase + 8 * g);
      acc[c] = __builtin_amdgcn_mfma_f32_16x16x32_bf16(ap, vf, acc[c], 0, 0, 0);
    }
  }

  // normalize and store fp32 output
  float li[4];
#pragma unroll
  for (int r = 0; r < 4; ++r) {
    float lv = __shfl(lsum, 4 * g + r);
    li[r] = 1.0f / lv;
  }
#pragma unroll
  for (int c = 0; c < 4; ++c)
#pragma unroll
    for (int r = 0; r < 4; ++r)
      out[((size_t)b * LSEQ + qbase + 4 * g + r) * HEADD + 16 * c + l15] = acc[c][r] * li[r];
}

// ---------------------------------------------------------------------------
extern "C" void kernel_launch(void* const* d_in, const int* in_sizes, int n_in,
                              void* d_out, int out_size, void* d_ws, size_t ws_size,
                              hipStream_t stream) {
  const float* idx_k = (const float*)d_in[0];
  const float* idx_q = (const float*)d_in[1];
  const float* idx_v = (const float*)d_in[2];
  // d_in[3] = msk : causal mask is applied analytically, never read
  const float* Wk = (const float*)d_in[4];
  const float* Wq = (const float*)d_in[5];
  const float* Wv = (const float*)d_in[6];
  float* out = (float*)d_out;

  char* ws = (char*)d_ws;
  const size_t WT_BYTES = (size_t)3 * 4 * 32 * 512 * 2;          // 384 KB packed W
  const size_t MAT_BYTES = (size_t)NBATCH * LSEQ * HEADD * 2;    // 2 MB each
  u16* wp = (u16*)ws;
  u16* Kb = (u16*)(ws + WT_BYTES);
  u16* Qb = (u16*)(ws + WT_BYTES + MAT_BYTES);
  u16* Vt = (u16*)(ws + WT_BYTES + 2 * MAT_BYTES);

  hipLaunchKernelGGL(wt_kernel, dim3(768), dim3(256), 0, stream, Wk, Wq, Wv, wp);
  hipLaunchKernelGGL(proj_kernel, dim3(256, 3), dim3(128), 0, stream,
                     idx_k, idx_q, idx_v, wp, Kb, Qb, Vt);
  hipLaunchKernelGGL(attn_kernel, dim3(64, NBATCH), dim3(128), 0, stream, Kb, Qb, Vt, out);
}